// Round 4
// baseline (949.798 us; speedup 1.0000x reference)
//
#include <hip/hip_runtime.h>
#include <hip/hip_bf16.h>
#include <math.h>

// MambaActorCritic: B=2048, OBS=512, D_MODEL=1024, D_INNER=2048, D_STATE=16,
// D_CONV=4, DT_RANK=64, ACT=18. All inputs/outputs fp32; big GEMMs in bf16 MFMA.
//
// v5 changes vs v4 (859us; ssm_heads measured 240us @ 1.78TB/s, latency-bound):
//  - ssm_heads restructured: phase0 computes dt for all 2048 channels into LDS
//    (1 ch/thread/pass, dt_w rows as 16 independent float4 L2 loads, no shfl);
//    phase1 does the state update with 1 LANE PER CHANNEL (4x float4 = 64B
//    contiguous per lane, ~10 independent loads in flight, lane-local C-dot,
//    zero cross-lane ops). Removes the shfl-serialized dt->state dependency
//    chain that capped the kernel at 22% HBM BW.
//  - everything else unchanged from v4 for clean attribution.

#define BATCH 2048
#define OBSD 512
#define DMODEL 1024
#define DINNER 2048
#define DSTATE 16
#define DTRANK 64
#define NACT 18

typedef __attribute__((ext_vector_type(8))) short shortx8;
typedef __attribute__((ext_vector_type(4))) float floatx4;

__device__ inline float sig_(float x) { return 1.f / (1.f + __expf(-x)); }

__device__ inline unsigned short bfc(float x) {
    __hip_bfloat16 h = __float2bfloat16(x);
    return *(unsigned short*)&h;
}

__device__ inline void store_bf4(unsigned short* dst, float4 v) {
    ushort4 u;
    u.x = bfc(v.x); u.y = bfc(v.y); u.z = bfc(v.z); u.w = bfc(v.w);
    *(ushort4*)dst = u;
}

// ---------------------------------------------------------------------------
// convert (blocks 0..5919) + fold_heads (blocks 5920..6071).
// ---------------------------------------------------------------------------
__global__ __launch_bounds__(256) void convert_fold_kernel(
    const float* __restrict__ obs, const float* __restrict__ w1,
    const float* __restrict__ w2, const float* __restrict__ w3,
    const float* __restrict__ Alog, const float* __restrict__ opw,
    const float* __restrict__ pol_w, const float* __restrict__ val_w,
    unsigned short* __restrict__ obs_bf, unsigned short* __restrict__ w1_bf,
    unsigned short* __restrict__ w2_bf, unsigned short* __restrict__ w3_bf,
    float* __restrict__ A_neg, float* __restrict__ Wc)
{
    int blk = blockIdx.x;
    if (blk >= 5920) {
        __shared__ float hw[1024];
        int idx = blk - 5920;        // 0..151
        int j = idx % 19;
        int dblk = idx / 19;         // 0..7
        const float* src = (j < 18) ? (pol_w + j * 1024) : val_w;
        for (int t = threadIdx.x; t < 1024; t += 256) hw[t] = src[t];
        __syncthreads();
        int d = dblk * 256 + threadIdx.x;
        float acc = 0.f;
#pragma unroll 8
        for (int m = 0; m < 1024; ++m)
            acc += hw[m] * opw[(size_t)m * 2048 + d];
        Wc[j * 2048 + d] = acc;
        return;
    }
    int g = blk * 256 + threadIdx.x;
    if (g < 262144) {
        store_bf4(obs_bf + g * 4, ((const float4*)obs)[g]);
    } else if (g < 393216) {
        int t = g - 262144;
        store_bf4(w1_bf + t * 4, ((const float4*)w1)[t]);
    } else if (g < 1441792) {
        int t = g - 393216;
        store_bf4(w2_bf + t * 4, ((const float4*)w2)[t]);
    } else if (g < 1507328) {
        int t = g - 1441792;
        int e = t * 4;
        int n = e >> 11;
        int k = e & 2047;
        float4 v = {0.f, 0.f, 0.f, 0.f};
        if (n < 96) v = *(const float4*)(w3 + n * 2048 + k);
        store_bf4(w3_bf + e, v);
    } else {
        int t = g - 1507328;  // < 8192
        float4 v = ((const float4*)Alog)[t];
        float4 o = {-__expf(v.x), -__expf(v.y), -__expf(v.z), -__expf(v.w)};
        ((float4*)A_neg)[t] = o;
    }
}

// ---------------------------------------------------------------------------
// staging helper: one 128x32 bf16 tile pair via global_load_lds width-16.
// ---------------------------------------------------------------------------
__device__ __forceinline__ void stage_tile(
    const short* Abase, const short* Bbase, short* As, short* Bs,
    int K, int k0, int wave, int r0, int c0, int r1, int c1)
{
    __builtin_amdgcn_global_load_lds(
        (const __attribute__((address_space(1))) unsigned int*)(Abase + (size_t)r0 * K + k0 + c0),
        (__attribute__((address_space(3))) unsigned int*)(As + wave * 512), 16, 0, 0);
    __builtin_amdgcn_global_load_lds(
        (const __attribute__((address_space(1))) unsigned int*)(Abase + (size_t)r1 * K + k0 + c1),
        (__attribute__((address_space(3))) unsigned int*)(As + 2048 + wave * 512), 16, 0, 0);
    __builtin_amdgcn_global_load_lds(
        (const __attribute__((address_space(1))) unsigned int*)(Bbase + (size_t)r0 * K + k0 + c0),
        (__attribute__((address_space(3))) unsigned int*)(Bs + wave * 512), 16, 0, 0);
    __builtin_amdgcn_global_load_lds(
        (const __attribute__((address_space(1))) unsigned int*)(Bbase + (size_t)r1 * K + k0 + c1),
        (__attribute__((address_space(3))) unsigned int*)(Bs + 2048 + wave * 512), 16, 0, 0);
}

// ---------------------------------------------------------------------------
// bf16 MFMA GEMM: C[M,N] = A[M,K] * B[N,K]^T. 128x128 tile, 4 waves, BK=32,
// double-buffered 2-phase K-loop (stage t+1 || compute t).
// ---------------------------------------------------------------------------
template <int BF16OUT, int BIAS, int SPLITK>
__global__ __launch_bounds__(256) void gemm_bt(
    const short* __restrict__ A, const short* __restrict__ Bm,
    void* __restrict__ Cout, const float* __restrict__ bias,
    int M, int N, int K, int ksplit_len)
{
    __shared__ short As[2][128 * 32];
    __shared__ short Bs[2][128 * 32];

    const int tid  = threadIdx.x;
    const int wave = tid >> 6;
    const int lane = tid & 63;
    const int quad = lane >> 4;
    const int l16  = lane & 15;
    const int wm   = (wave & 1) << 6;
    const int wn   = (wave >> 1) << 6;
    const int bm   = blockIdx.x;
    const int bn   = blockIdx.y;

    int kbeg = 0, kend = K;
    if (SPLITK) { kbeg = blockIdx.z * ksplit_len; kend = kbeg + ksplit_len; }

    floatx4 acc[4][4] = {};

    const int v0 = tid * 8;
    const int r0 = v0 >> 5, c0 = v0 & 31;
    const int v1 = (256 + tid) * 8;
    const int r1 = v1 >> 5, c1 = v1 & 31;

    const short* Abase = A + (size_t)bm * 128 * K;
    const short* Bbase = Bm + (size_t)bn * 128 * K;

    stage_tile(Abase, Bbase, As[0], Bs[0], K, kbeg, wave, r0, c0, r1, c1);
    __syncthreads();  // vmcnt(0) drain -> buf0 ready

    int cur = 0;
    for (int k0 = kbeg; k0 < kend; k0 += 32) {
        if (k0 + 32 < kend)
            stage_tile(Abase, Bbase, As[cur ^ 1], Bs[cur ^ 1], K, k0 + 32,
                       wave, r0, c0, r1, c1);
        shortx8 af[4], bfv[4];
#pragma unroll
        for (int i = 0; i < 4; ++i)
            af[i] = *(const shortx8*)(As[cur] + (wm + i * 16 + l16) * 32 + quad * 8);
#pragma unroll
        for (int j = 0; j < 4; ++j)
            bfv[j] = *(const shortx8*)(Bs[cur] + (wn + j * 16 + l16) * 32 + quad * 8);
#pragma unroll
        for (int i = 0; i < 4; ++i)
#pragma unroll
            for (int j = 0; j < 4; ++j)
                acc[i][j] = __builtin_amdgcn_mfma_f32_16x16x32_bf16(af[i], bfv[j], acc[i][j], 0, 0, 0);
        __syncthreads();  // drains next-stage vmcnt; next iter reads buf^1
        cur ^= 1;
    }

    // epilogue: C/D layout col(n)=lane&15, row(m)=quad*4+reg  [m89-verified]
    if (BF16OUT) {
        unsigned short* C = (unsigned short*)Cout;
#pragma unroll
        for (int i = 0; i < 4; ++i) {
            int gm = bm * 128 + wm + i * 16 + quad * 4;
#pragma unroll
            for (int j = 0; j < 4; ++j) {
                int gn = bn * 128 + wn + j * 16 + l16;
                float bv = BIAS ? bias[gn] : 0.f;
#pragma unroll
                for (int r = 0; r < 4; ++r)
                    C[(size_t)(gm + r) * N + gn] = bfc(acc[i][j][r] + bv);
            }
        }
    } else {
        float* C = (float*)Cout;
        if (SPLITK) C += (size_t)blockIdx.z * M * N;
#pragma unroll
        for (int i = 0; i < 4; ++i) {
            int gm = bm * 128 + wm + i * 16 + quad * 4;
#pragma unroll
            for (int j = 0; j < 4; ++j) {
                int gn = bn * 128 + wn + j * 16 + l16;
                float bv = BIAS ? bias[gn] : 0.f;
#pragma unroll
                for (int r = 0; r < 4; ++r)
                    C[(size_t)(gm + r) * N + gn] = acc[i][j][r] + bv;
            }
        }
    }
}

// ---------------------------------------------------------------------------
// G2 with fused conv/z epilogue: xz = h @ mamba_in_w.T (M=2048, N=4096, K=1024)
// ---------------------------------------------------------------------------
__global__ __launch_bounds__(256) void gemm_g2(
    const short* __restrict__ A, const short* __restrict__ Bm,
    const float* __restrict__ conv_state, const float* __restrict__ conv_w,
    const float* __restrict__ conv_b, float* __restrict__ conv_out,
    float* __restrict__ x_conv, unsigned short* __restrict__ x_conv_bf,
    float* __restrict__ zs, int K)
{
    __shared__ short As[2][128 * 32];
    __shared__ short Bs[2][128 * 32];

    const int tid  = threadIdx.x;
    const int wave = tid >> 6;
    const int lane = tid & 63;
    const int quad = lane >> 4;
    const int l16  = lane & 15;
    const int wm   = (wave & 1) << 6;
    const int wn   = (wave >> 1) << 6;
    const int bm   = blockIdx.x;
    const int bn   = blockIdx.y;

    floatx4 acc[4][4] = {};

    const int v0 = tid * 8;
    const int r0 = v0 >> 5, c0 = v0 & 31;
    const int v1 = (256 + tid) * 8;
    const int r1 = v1 >> 5, c1 = v1 & 31;

    const short* Abase = A + (size_t)bm * 128 * K;
    const short* Bbase = Bm + (size_t)bn * 128 * K;

    stage_tile(Abase, Bbase, As[0], Bs[0], K, 0, wave, r0, c0, r1, c1);
    __syncthreads();

    int cur = 0;
    for (int k0 = 0; k0 < K; k0 += 32) {
        if (k0 + 32 < K)
            stage_tile(Abase, Bbase, As[cur ^ 1], Bs[cur ^ 1], K, k0 + 32,
                       wave, r0, c0, r1, c1);
        shortx8 af[4], bfv[4];
#pragma unroll
        for (int i = 0; i < 4; ++i)
            af[i] = *(const shortx8*)(As[cur] + (wm + i * 16 + l16) * 32 + quad * 8);
#pragma unroll
        for (int j = 0; j < 4; ++j)
            bfv[j] = *(const shortx8*)(Bs[cur] + (wn + j * 16 + l16) * 32 + quad * 8);
#pragma unroll
        for (int i = 0; i < 4; ++i)
#pragma unroll
            for (int j = 0; j < 4; ++j)
                acc[i][j] = __builtin_amdgcn_mfma_f32_16x16x32_bf16(af[i], bfv[j], acc[i][j], 0, 0, 0);
        __syncthreads();
        cur ^= 1;
    }

    // fused epilogue; bn<16 -> x half, else z half (block-uniform branch)
    if (bn < 16) {
#pragma unroll
        for (int j = 0; j < 4; ++j) {
            int d = bn * 128 + wn + j * 16 + l16;          // 0..2047
            float4 w4 = *(const float4*)(conv_w + d * 4);
            float cb = conv_b[d];
#pragma unroll
            for (int i = 0; i < 4; ++i) {
                int gm = bm * 128 + wm + i * 16 + quad * 4;
#pragma unroll
                for (int r = 0; r < 4; ++r) {
                    size_t idx = (size_t)(gm + r) * 2048 + d;
                    float xv = acc[i][j][r];
                    float4 cs = *(const float4*)(conv_state + idx * 4);
                    float s = cs.y * w4.x + cs.z * w4.y + cs.w * w4.z + xv * w4.w + cb;
                    float xc = s * sig_(s);
                    float4 outv = {cs.y, cs.z, cs.w, xv};
                    *(float4*)(conv_out + idx * 4) = outv;
                    x_conv[idx] = xc;
                    x_conv_bf[idx] = bfc(xc);
                }
            }
        }
    } else {
#pragma unroll
        for (int j = 0; j < 4; ++j) {
            int d = bn * 128 + wn + j * 16 + l16 - 2048;   // 0..2047
#pragma unroll
            for (int i = 0; i < 4; ++i) {
                int gm = bm * 128 + wm + i * 16 + quad * 4;
#pragma unroll
                for (int r = 0; r < 4; ++r) {
                    float zv = acc[i][j][r];
                    zs[(size_t)(gm + r) * 2048 + d] = zv * sig_(zv);
                }
            }
        }
    }
}

// sum split-K partials: x_db[b][n] (n<96) = sum_z part[z][b][n] (ld 128)
__global__ __launch_bounds__(256) void reduce_g3(
    const float* __restrict__ part, float* __restrict__ x_db)
{
    int idx = blockIdx.x * 256 + threadIdx.x;  // over 2048*96
    int b = idx / 96, n = idx - b * 96;
    float s = 0.f;
#pragma unroll
    for (int z = 0; z < 8; ++z)
        s += part[(size_t)z * BATCH * 128 + b * 128 + n];
    x_db[idx] = s;
}

// ---------------------------------------------------------------------------
// Fused dt + SSM + heads, latency-optimized. One block per batch row.
// Phase 0: dt for all 2048 channels -> LDS. 1 channel/thread/pass, 8 passes;
//          dt_w row = 16 independent float4 loads (L2), no cross-lane ops.
// Phase 1: state update, 1 LANE PER CHANNEL, 8 rounds of 256 channels.
//          Per lane: 4x float4 ssm_state (64B contiguous) + 4x float4 A_neg +
//          scalars, 16 exp, lane-local C-dot, 4x float4 store. ~10 independent
//          global loads in flight per lane; zero shfl.
// Phase 2: heads (19 dots over yrow).
// ---------------------------------------------------------------------------
__global__ __launch_bounds__(256) void ssm_heads_kernel(
    const float* __restrict__ ssm_state, const float* __restrict__ x_conv,
    const float* __restrict__ zs, const float* __restrict__ x_db,
    const float* __restrict__ dt_w, const float* __restrict__ dt_b,
    const float* __restrict__ A_neg, const float* __restrict__ Dvec,
    const float* __restrict__ Wc, const float* __restrict__ pol_b,
    const float* __restrict__ val_b, float* __restrict__ ssm_out,
    float* __restrict__ logits, float* __restrict__ value)
{
    __shared__ float sh[96];   // [0:64) dt-rank row, [64:80) B, [80:96) C
    __shared__ float dtsh[2048];
    __shared__ __align__(16) float yrow[2048];
    int b = blockIdx.x;
    int tid = threadIdx.x;
    if (tid < 96) sh[tid] = x_db[b * 96 + tid];
    __syncthreads();

    // phase 0: dt
#pragma unroll 2
    for (int p = 0; p < 8; ++p) {
        int d = p * 256 + tid;
        const float4* w4 = (const float4*)(dt_w + (size_t)d * 64);
        float acc = dt_b[d];
#pragma unroll
        for (int i = 0; i < 16; ++i) {
            float4 wv = w4[i];
            acc += sh[i * 4 + 0] * wv.x + sh[i * 4 + 1] * wv.y +
                   sh[i * 4 + 2] * wv.z + sh[i * 4 + 3] * wv.w;
        }
        dtsh[d] = acc > 20.f ? acc : log1pf(__expf(acc));
    }
    __syncthreads();

    // phase 1: state update (lane-local, no cross-lane ops)
    float B0 = sh[64], B1 = sh[65], B2 = sh[66], B3 = sh[67];
    float B4 = sh[68], B5 = sh[69], B6 = sh[70], B7 = sh[71];
    float B8 = sh[72], B9 = sh[73], Ba = sh[74], Bb = sh[75];
    float Bc = sh[76], Bd = sh[77], Be = sh[78], Bf = sh[79];
    for (int p = 0; p < 8; ++p) {
        int d = p * 256 + tid;
        size_t idx = (size_t)b * 2048 + d;
        float x  = x_conv[idx];
        float zv = zs[idx];
        float dt = dtsh[d];
        float Dd = Dvec[d];
        float xdt = x * dt;
        const float4* S = (const float4*)(ssm_state + idx * 16);
        const float4* A = (const float4*)(A_neg + (size_t)d * 16);
        float4* O = (float4*)(ssm_out + idx * 16);
        float4 s0 = S[0], s1 = S[1], s2 = S[2], s3 = S[3];
        float4 a0 = A[0], a1 = A[1], a2 = A[2], a3 = A[3];
        float4 o0, o1, o2, o3;
        o0.x = s0.x * __expf(dt * a0.x) + xdt * B0;
        o0.y = s0.y * __expf(dt * a0.y) + xdt * B1;
        o0.z = s0.z * __expf(dt * a0.z) + xdt * B2;
        o0.w = s0.w * __expf(dt * a0.w) + xdt * B3;
        o1.x = s1.x * __expf(dt * a1.x) + xdt * B4;
        o1.y = s1.y * __expf(dt * a1.y) + xdt * B5;
        o1.z = s1.z * __expf(dt * a1.z) + xdt * B6;
        o1.w = s1.w * __expf(dt * a1.w) + xdt * B7;
        o2.x = s2.x * __expf(dt * a2.x) + xdt * B8;
        o2.y = s2.y * __expf(dt * a2.y) + xdt * B9;
        o2.z = s2.z * __expf(dt * a2.z) + xdt * Ba;
        o2.w = s2.w * __expf(dt * a2.w) + xdt * Bb;
        o3.x = s3.x * __expf(dt * a3.x) + xdt * Bc;
        o3.y = s3.y * __expf(dt * a3.y) + xdt * Bd;
        o3.z = s3.z * __expf(dt * a3.z) + xdt * Be;
        o3.w = s3.w * __expf(dt * a3.w) + xdt * Bf;
        O[0] = o0; O[1] = o1; O[2] = o2; O[3] = o3;
        float y;
        y  = o0.x * sh[80] + o0.y * sh[81] + o0.z * sh[82] + o0.w * sh[83];
        y += o1.x * sh[84] + o1.y * sh[85] + o1.z * sh[86] + o1.w * sh[87];
        y += o2.x * sh[88] + o2.y * sh[89] + o2.z * sh[90] + o2.w * sh[91];
        y += o3.x * sh[92] + o3.y * sh[93] + o3.z * sh[94] + o3.w * sh[95];
        y += Dd * x;
        yrow[d] = y * zv;
    }
    __syncthreads();

    // phase 2: heads
    int wave = tid >> 6, lane = tid & 63;
    for (int j = wave; j < 19; j += 4) {
        const float4* w = (const float4*)(Wc + j * 2048);
        float p = 0.f;
        for (int k4 = lane; k4 < 512; k4 += 64) {
            float4 wv = w[k4];
            float4 rv = ((const float4*)yrow)[k4];
            p += rv.x * wv.x + rv.y * wv.y + rv.z * wv.z + rv.w * wv.w;
        }
#pragma unroll
        for (int off = 32; off; off >>= 1) p += __shfl_down(p, off);
        if (lane == 0) {
            if (j < 18) logits[b * NACT + j] = p + pol_b[j];
            else        value[b] = p + val_b[0];
        }
    }
}

// ---------------------------------------------------------------------------
extern "C" void kernel_launch(void* const* d_in, const int* in_sizes, int n_in,
                              void* d_out, int out_size, void* d_ws, size_t ws_size,
                              hipStream_t stream)
{
    const float* obs        = (const float*)d_in[0];
    const float* conv_state = (const float*)d_in[1];
    const float* ssm_state  = (const float*)d_in[2];
    const float* in_proj_w  = (const float*)d_in[3];
    const float* in_proj_b  = (const float*)d_in[4];
    const float* mamba_in_w = (const float*)d_in[5];
    const float* conv_w     = (const float*)d_in[6];
    const float* conv_b     = (const float*)d_in[7];
    const float* x_proj_w   = (const float*)d_in[8];
    const float* dt_w       = (const float*)d_in[9];
    const float* dt_b       = (const float*)d_in[10];
    const float* A_log      = (const float*)d_in[11];
    const float* Dvec       = (const float*)d_in[12];
    const float* out_proj_w = (const float*)d_in[13];
    const float* pol_w      = (const float*)d_in[14];
    const float* pol_b      = (const float*)d_in[15];
    const float* val_w      = (const float*)d_in[16];
    const float* val_b      = (const float*)d_in[17];

    // workspace layout (bytes)
    char* ws = (char*)d_ws;
    unsigned short* obs_bf    = (unsigned short*)(ws + 0);          // 2048x512 bf16
    unsigned short* w1_bf     = (unsigned short*)(ws + 2097152);    // 1024x512
    unsigned short* w2_bf     = (unsigned short*)(ws + 3145728);    // 4096x1024
    unsigned short* w3_bf     = (unsigned short*)(ws + 11534336);   // 128x2048 (padded)
    float*          A_neg     = (float*)(ws + 12058624);            // 2048x16
    unsigned short* h_bf      = (unsigned short*)(ws + 12189696);   // 2048x1024
    float*          x_conv    = (float*)(ws + 16384000);            // 2048x2048 fp32
    unsigned short* x_conv_bf = (unsigned short*)(ws + 33161216);   // 2048x2048 bf16
    float*          zs        = (float*)(ws + 41549824);            // 2048x2048 fp32
    float*          g3_part   = (float*)(ws + 58327040);            // 8x2048x128
    float*          x_db      = (float*)(ws + 66715648);            // 2048x96
    float*          Wc        = (float*)(ws + 67502080);            // 19x2048
    // total = 67,657,728 bytes
    if (ws_size < 67657728) return;  // insufficient workspace -> fail loudly

    float* logits   = (float*)d_out;                       // 2048x18
    float* value    = logits + (size_t)BATCH * NACT;       // 2048
    float* conv_out = value + BATCH;                       // 2048x2048x4
    float* ssm_out  = conv_out + (size_t)BATCH * DINNER * 4;  // 2048x2048x16

    // convert + fold_heads (Wc = [pol_w; val_w] @ out_proj_w)
    convert_fold_kernel<<<6072, 256, 0, stream>>>(
        obs, in_proj_w, mamba_in_w, x_proj_w, A_log, out_proj_w, pol_w, val_w,
        obs_bf, w1_bf, w2_bf, w3_bf, A_neg, Wc);

    // G1: h = obs @ in_proj_w.T + b  -> bf16
    gemm_bt<1, 1, 0><<<dim3(16, 8), 256, 0, stream>>>(
        (const short*)obs_bf, (const short*)w1_bf, h_bf, in_proj_b, 2048, 1024, 512, 0);

    // G2: xz = h @ mamba_in_w.T with fused conv (x half) + z*sig(z) (z half)
    gemm_g2<<<dim3(16, 32), 256, 0, stream>>>(
        (const short*)h_bf, (const short*)w2_bf, conv_state, conv_w, conv_b,
        conv_out, x_conv, x_conv_bf, zs, 1024);

    // G3: x_db = x_conv @ x_proj_w.T  (N padded 96->128, split-K=8)
    gemm_bt<0, 0, 1><<<dim3(16, 1, 8), 256, 0, stream>>>(
        (const short*)x_conv_bf, (const short*)w3_bf, g3_part, nullptr, 2048, 128, 2048, 256);

    // split-K reduce: x_db[2048][96] (single pass over g3_part)
    reduce_g3<<<768, 256, 0, stream>>>(g3_part, x_db);

    // fused dt + SSM + heads
    ssm_heads_kernel<<<2048, 256, 0, stream>>>(
        ssm_state, x_conv, zs, x_db, dt_w, dt_b, A_neg, Dvec, Wc, pol_b, val_b,
        ssm_out, logits, value);
}

// Round 5
// 928.533 us; speedup vs baseline: 1.0229x; 1.0229x over previous
//
#include <hip/hip_runtime.h>
#include <hip/hip_bf16.h>
#include <math.h>

// MambaActorCritic: B=2048, OBS=512, D_MODEL=1024, D_INNER=2048, D_STATE=16,
// D_CONV=4, DT_RANK=64, ACT=18. All inputs/outputs fp32; big GEMMs in bf16 MFMA.
//
// v6 changes vs v4 (859us; ssm_heads 240us @1.78TB/s) / v5 (950us, regression):
//  - ssm_out + conv_out written with NON-TEMPORAL stores: streamed past L3 so
//    the 256MB Infinity Cache retains ssm_state (268MB) across iterations.
//    (v4 FETCH=154MB < 268MB proves L3 was partially serving ssm_state; the
//    write-allocate stream was evicting it -> thrash-inflated miss latency.)
//  - ssm_heads: dt computed in phase0 into LDS (no shfl chain; v5's idea),
//    phase1 back to v4's COALESCED 4-lane q-split (v5's 64B-stride layout
//    reverted) with #pragma unroll 4 for memory-level parallelism.
//  - everything else unchanged from v4.

#define BATCH 2048
#define OBSD 512
#define DMODEL 1024
#define DINNER 2048
#define DSTATE 16
#define DTRANK 64
#define NACT 18

typedef __attribute__((ext_vector_type(8))) short shortx8;
typedef __attribute__((ext_vector_type(4))) float floatx4;

__device__ inline float sig_(float x) { return 1.f / (1.f + __expf(-x)); }

__device__ inline unsigned short bfc(float x) {
    __hip_bfloat16 h = __float2bfloat16(x);
    return *(unsigned short*)&h;
}

__device__ inline void store_bf4(unsigned short* dst, float4 v) {
    ushort4 u;
    u.x = bfc(v.x); u.y = bfc(v.y); u.z = bfc(v.z); u.w = bfc(v.w);
    *(ushort4*)dst = u;
}

__device__ inline void ntstore4(float* p, floatx4 v) {
    __builtin_nontemporal_store(v, (floatx4*)p);
}

// ---------------------------------------------------------------------------
// convert (blocks 0..5919) + fold_heads (blocks 5920..6071).
// ---------------------------------------------------------------------------
__global__ __launch_bounds__(256) void convert_fold_kernel(
    const float* __restrict__ obs, const float* __restrict__ w1,
    const float* __restrict__ w2, const float* __restrict__ w3,
    const float* __restrict__ Alog, const float* __restrict__ opw,
    const float* __restrict__ pol_w, const float* __restrict__ val_w,
    unsigned short* __restrict__ obs_bf, unsigned short* __restrict__ w1_bf,
    unsigned short* __restrict__ w2_bf, unsigned short* __restrict__ w3_bf,
    float* __restrict__ A_neg, float* __restrict__ Wc)
{
    int blk = blockIdx.x;
    if (blk >= 5920) {
        __shared__ float hw[1024];
        int idx = blk - 5920;        // 0..151
        int j = idx % 19;
        int dblk = idx / 19;         // 0..7
        const float* src = (j < 18) ? (pol_w + j * 1024) : val_w;
        for (int t = threadIdx.x; t < 1024; t += 256) hw[t] = src[t];
        __syncthreads();
        int d = dblk * 256 + threadIdx.x;
        float acc = 0.f;
#pragma unroll 8
        for (int m = 0; m < 1024; ++m)
            acc += hw[m] * opw[(size_t)m * 2048 + d];
        Wc[j * 2048 + d] = acc;
        return;
    }
    int g = blk * 256 + threadIdx.x;
    if (g < 262144) {
        store_bf4(obs_bf + g * 4, ((const float4*)obs)[g]);
    } else if (g < 393216) {
        int t = g - 262144;
        store_bf4(w1_bf + t * 4, ((const float4*)w1)[t]);
    } else if (g < 1441792) {
        int t = g - 393216;
        store_bf4(w2_bf + t * 4, ((const float4*)w2)[t]);
    } else if (g < 1507328) {
        int t = g - 1441792;
        int e = t * 4;
        int n = e >> 11;
        int k = e & 2047;
        float4 v = {0.f, 0.f, 0.f, 0.f};
        if (n < 96) v = *(const float4*)(w3 + n * 2048 + k);
        store_bf4(w3_bf + e, v);
    } else {
        int t = g - 1507328;  // < 8192
        float4 v = ((const float4*)Alog)[t];
        float4 o = {-__expf(v.x), -__expf(v.y), -__expf(v.z), -__expf(v.w)};
        ((float4*)A_neg)[t] = o;
    }
}

// ---------------------------------------------------------------------------
// staging helper: one 128x32 bf16 tile pair via global_load_lds width-16.
// ---------------------------------------------------------------------------
__device__ __forceinline__ void stage_tile(
    const short* Abase, const short* Bbase, short* As, short* Bs,
    int K, int k0, int wave, int r0, int c0, int r1, int c1)
{
    __builtin_amdgcn_global_load_lds(
        (const __attribute__((address_space(1))) unsigned int*)(Abase + (size_t)r0 * K + k0 + c0),
        (__attribute__((address_space(3))) unsigned int*)(As + wave * 512), 16, 0, 0);
    __builtin_amdgcn_global_load_lds(
        (const __attribute__((address_space(1))) unsigned int*)(Abase + (size_t)r1 * K + k0 + c1),
        (__attribute__((address_space(3))) unsigned int*)(As + 2048 + wave * 512), 16, 0, 0);
    __builtin_amdgcn_global_load_lds(
        (const __attribute__((address_space(1))) unsigned int*)(Bbase + (size_t)r0 * K + k0 + c0),
        (__attribute__((address_space(3))) unsigned int*)(Bs + wave * 512), 16, 0, 0);
    __builtin_amdgcn_global_load_lds(
        (const __attribute__((address_space(1))) unsigned int*)(Bbase + (size_t)r1 * K + k0 + c1),
        (__attribute__((address_space(3))) unsigned int*)(Bs + 2048 + wave * 512), 16, 0, 0);
}

// ---------------------------------------------------------------------------
// bf16 MFMA GEMM: C[M,N] = A[M,K] * B[N,K]^T. 128x128 tile, 4 waves, BK=32,
// double-buffered 2-phase K-loop (stage t+1 || compute t).
// ---------------------------------------------------------------------------
template <int BF16OUT, int BIAS, int SPLITK>
__global__ __launch_bounds__(256) void gemm_bt(
    const short* __restrict__ A, const short* __restrict__ Bm,
    void* __restrict__ Cout, const float* __restrict__ bias,
    int M, int N, int K, int ksplit_len)
{
    __shared__ short As[2][128 * 32];
    __shared__ short Bs[2][128 * 32];

    const int tid  = threadIdx.x;
    const int wave = tid >> 6;
    const int lane = tid & 63;
    const int quad = lane >> 4;
    const int l16  = lane & 15;
    const int wm   = (wave & 1) << 6;
    const int wn   = (wave >> 1) << 6;
    const int bm   = blockIdx.x;
    const int bn   = blockIdx.y;

    int kbeg = 0, kend = K;
    if (SPLITK) { kbeg = blockIdx.z * ksplit_len; kend = kbeg + ksplit_len; }

    floatx4 acc[4][4] = {};

    const int v0 = tid * 8;
    const int r0 = v0 >> 5, c0 = v0 & 31;
    const int v1 = (256 + tid) * 8;
    const int r1 = v1 >> 5, c1 = v1 & 31;

    const short* Abase = A + (size_t)bm * 128 * K;
    const short* Bbase = Bm + (size_t)bn * 128 * K;

    stage_tile(Abase, Bbase, As[0], Bs[0], K, kbeg, wave, r0, c0, r1, c1);
    __syncthreads();  // vmcnt(0) drain -> buf0 ready

    int cur = 0;
    for (int k0 = kbeg; k0 < kend; k0 += 32) {
        if (k0 + 32 < kend)
            stage_tile(Abase, Bbase, As[cur ^ 1], Bs[cur ^ 1], K, k0 + 32,
                       wave, r0, c0, r1, c1);
        shortx8 af[4], bfv[4];
#pragma unroll
        for (int i = 0; i < 4; ++i)
            af[i] = *(const shortx8*)(As[cur] + (wm + i * 16 + l16) * 32 + quad * 8);
#pragma unroll
        for (int j = 0; j < 4; ++j)
            bfv[j] = *(const shortx8*)(Bs[cur] + (wn + j * 16 + l16) * 32 + quad * 8);
#pragma unroll
        for (int i = 0; i < 4; ++i)
#pragma unroll
            for (int j = 0; j < 4; ++j)
                acc[i][j] = __builtin_amdgcn_mfma_f32_16x16x32_bf16(af[i], bfv[j], acc[i][j], 0, 0, 0);
        __syncthreads();  // drains next-stage vmcnt; next iter reads buf^1
        cur ^= 1;
    }

    // epilogue: C/D layout col(n)=lane&15, row(m)=quad*4+reg  [m89-verified]
    if (BF16OUT) {
        unsigned short* C = (unsigned short*)Cout;
#pragma unroll
        for (int i = 0; i < 4; ++i) {
            int gm = bm * 128 + wm + i * 16 + quad * 4;
#pragma unroll
            for (int j = 0; j < 4; ++j) {
                int gn = bn * 128 + wn + j * 16 + l16;
                float bv = BIAS ? bias[gn] : 0.f;
#pragma unroll
                for (int r = 0; r < 4; ++r)
                    C[(size_t)(gm + r) * N + gn] = bfc(acc[i][j][r] + bv);
            }
        }
    } else {
        float* C = (float*)Cout;
        if (SPLITK) C += (size_t)blockIdx.z * M * N;
#pragma unroll
        for (int i = 0; i < 4; ++i) {
            int gm = bm * 128 + wm + i * 16 + quad * 4;
#pragma unroll
            for (int j = 0; j < 4; ++j) {
                int gn = bn * 128 + wn + j * 16 + l16;
                float bv = BIAS ? bias[gn] : 0.f;
#pragma unroll
                for (int r = 0; r < 4; ++r)
                    C[(size_t)(gm + r) * N + gn] = acc[i][j][r] + bv;
            }
        }
    }
}

// ---------------------------------------------------------------------------
// G2 with fused conv/z epilogue: xz = h @ mamba_in_w.T (M=2048, N=4096, K=1024)
// conv_out written non-temporally (never re-read; keep L3 for live tensors).
// ---------------------------------------------------------------------------
__global__ __launch_bounds__(256) void gemm_g2(
    const short* __restrict__ A, const short* __restrict__ Bm,
    const float* __restrict__ conv_state, const float* __restrict__ conv_w,
    const float* __restrict__ conv_b, float* __restrict__ conv_out,
    float* __restrict__ x_conv, unsigned short* __restrict__ x_conv_bf,
    float* __restrict__ zs, int K)
{
    __shared__ short As[2][128 * 32];
    __shared__ short Bs[2][128 * 32];

    const int tid  = threadIdx.x;
    const int wave = tid >> 6;
    const int lane = tid & 63;
    const int quad = lane >> 4;
    const int l16  = lane & 15;
    const int wm   = (wave & 1) << 6;
    const int wn   = (wave >> 1) << 6;
    const int bm   = blockIdx.x;
    const int bn   = blockIdx.y;

    floatx4 acc[4][4] = {};

    const int v0 = tid * 8;
    const int r0 = v0 >> 5, c0 = v0 & 31;
    const int v1 = (256 + tid) * 8;
    const int r1 = v1 >> 5, c1 = v1 & 31;

    const short* Abase = A + (size_t)bm * 128 * K;
    const short* Bbase = Bm + (size_t)bn * 128 * K;

    stage_tile(Abase, Bbase, As[0], Bs[0], K, 0, wave, r0, c0, r1, c1);
    __syncthreads();

    int cur = 0;
    for (int k0 = 0; k0 < K; k0 += 32) {
        if (k0 + 32 < K)
            stage_tile(Abase, Bbase, As[cur ^ 1], Bs[cur ^ 1], K, k0 + 32,
                       wave, r0, c0, r1, c1);
        shortx8 af[4], bfv[4];
#pragma unroll
        for (int i = 0; i < 4; ++i)
            af[i] = *(const shortx8*)(As[cur] + (wm + i * 16 + l16) * 32 + quad * 8);
#pragma unroll
        for (int j = 0; j < 4; ++j)
            bfv[j] = *(const shortx8*)(Bs[cur] + (wn + j * 16 + l16) * 32 + quad * 8);
#pragma unroll
        for (int i = 0; i < 4; ++i)
#pragma unroll
            for (int j = 0; j < 4; ++j)
                acc[i][j] = __builtin_amdgcn_mfma_f32_16x16x32_bf16(af[i], bfv[j], acc[i][j], 0, 0, 0);
        __syncthreads();
        cur ^= 1;
    }

    // fused epilogue; bn<16 -> x half, else z half (block-uniform branch)
    if (bn < 16) {
#pragma unroll
        for (int j = 0; j < 4; ++j) {
            int d = bn * 128 + wn + j * 16 + l16;          // 0..2047
            float4 w4 = *(const float4*)(conv_w + d * 4);
            float cb = conv_b[d];
#pragma unroll
            for (int i = 0; i < 4; ++i) {
                int gm = bm * 128 + wm + i * 16 + quad * 4;
#pragma unroll
                for (int r = 0; r < 4; ++r) {
                    size_t idx = (size_t)(gm + r) * 2048 + d;
                    float xv = acc[i][j][r];
                    float4 cs = *(const float4*)(conv_state + idx * 4);
                    float s = cs.y * w4.x + cs.z * w4.y + cs.w * w4.z + xv * w4.w + cb;
                    float xc = s * sig_(s);
                    floatx4 outv = {cs.y, cs.z, cs.w, xv};
                    ntstore4(conv_out + idx * 4, outv);
                    x_conv[idx] = xc;
                    x_conv_bf[idx] = bfc(xc);
                }
            }
        }
    } else {
#pragma unroll
        for (int j = 0; j < 4; ++j) {
            int d = bn * 128 + wn + j * 16 + l16 - 2048;   // 0..2047
#pragma unroll
            for (int i = 0; i < 4; ++i) {
                int gm = bm * 128 + wm + i * 16 + quad * 4;
#pragma unroll
                for (int r = 0; r < 4; ++r) {
                    float zv = acc[i][j][r];
                    zs[(size_t)(gm + r) * 2048 + d] = zv * sig_(zv);
                }
            }
        }
    }
}

// sum split-K partials: x_db[b][n] (n<96) = sum_z part[z][b][n] (ld 128)
__global__ __launch_bounds__(256) void reduce_g3(
    const float* __restrict__ part, float* __restrict__ x_db)
{
    int idx = blockIdx.x * 256 + threadIdx.x;  // over 2048*96
    int b = idx / 96, n = idx - b * 96;
    float s = 0.f;
#pragma unroll
    for (int z = 0; z < 8; ++z)
        s += part[(size_t)z * BATCH * 128 + b * 128 + n];
    x_db[idx] = s;
}

// ---------------------------------------------------------------------------
// Fused dt + SSM + heads. One block per batch row.
// Phase 0: dt for all 2048 channels -> LDS (1 ch/thread/pass, no cross-lane).
// Phase 1: state update, 4-lane q-split (coalesced: wave covers 16 channels =
//          1KB contiguous per instruction), unroll 4 -> ~4 independent
//          HBM-load/exp chains in flight per lane. ssm_out stored
//          NON-TEMPORALLY so L3 keeps ssm_state resident.
// Phase 2: heads (19 dots over yrow).
// ---------------------------------------------------------------------------
__global__ __launch_bounds__(256) void ssm_heads_kernel(
    const float* __restrict__ ssm_state, const float* __restrict__ x_conv,
    const float* __restrict__ zs, const float* __restrict__ x_db,
    const float* __restrict__ dt_w, const float* __restrict__ dt_b,
    const float* __restrict__ A_neg, const float* __restrict__ Dvec,
    const float* __restrict__ Wc, const float* __restrict__ pol_b,
    const float* __restrict__ val_b, float* __restrict__ ssm_out,
    float* __restrict__ logits, float* __restrict__ value)
{
    __shared__ float sh[96];   // [0:64) dt-rank row, [64:80) B, [80:96) C
    __shared__ float dtsh[2048];
    __shared__ __align__(16) float yrow[2048];
    int b = blockIdx.x;
    int tid = threadIdx.x;
    if (tid < 96) sh[tid] = x_db[b * 96 + tid];
    __syncthreads();

    // phase 0: dt (split accumulators to break the FMA chain)
#pragma unroll 2
    for (int p = 0; p < 8; ++p) {
        int d = p * 256 + tid;
        const float4* w4 = (const float4*)(dt_w + (size_t)d * 64);
        float acc0 = dt_b[d], acc1 = 0.f;
#pragma unroll
        for (int i = 0; i < 8; ++i) {
            float4 wa = w4[i];
            float4 wb = w4[i + 8];
            acc0 += sh[i * 4 + 0] * wa.x + sh[i * 4 + 1] * wa.y +
                    sh[i * 4 + 2] * wa.z + sh[i * 4 + 3] * wa.w;
            acc1 += sh[32 + i * 4 + 0] * wb.x + sh[32 + i * 4 + 1] * wb.y +
                    sh[32 + i * 4 + 2] * wb.z + sh[32 + i * 4 + 3] * wb.w;
        }
        float acc = acc0 + acc1;
        dtsh[d] = acc > 20.f ? acc : log1pf(__expf(acc));
    }
    __syncthreads();

    // phase 1: state update, q-split, unroll 4 for MLP
    int q  = tid & 3;
    int dl = tid >> 2;             // 0..63
    floatx4 Bv = *(const floatx4*)(sh + 64 + q * 4);
    floatx4 Cv = *(const floatx4*)(sh + 80 + q * 4);
#pragma unroll 4
    for (int r = 0; r < 32; ++r) {
        int d = r * 64 + dl;
        size_t idx = (size_t)b * 2048 + d;
        float x  = x_conv[idx];
        float zv = zs[idx];
        float dt = dtsh[d];
        float Dd = Dvec[d];
        float xdt = x * dt;
        floatx4 s = *(const floatx4*)(ssm_state + idx * 16 + q * 4);
        floatx4 a = *(const floatx4*)(A_neg + (size_t)d * 16 + q * 4);
        floatx4 o;
        o.x = s.x * __expf(dt * a.x) + xdt * Bv.x;
        o.y = s.y * __expf(dt * a.y) + xdt * Bv.y;
        o.z = s.z * __expf(dt * a.z) + xdt * Bv.z;
        o.w = s.w * __expf(dt * a.w) + xdt * Bv.w;
        ntstore4(ssm_out + idx * 16 + q * 4, o);
        float p = o.x * Cv.x + o.y * Cv.y + o.z * Cv.z + o.w * Cv.w;
        p += __shfl_xor(p, 1);
        p += __shfl_xor(p, 2);
        if (q == 0) yrow[d] = (p + Dd * x) * zv;
    }
    __syncthreads();

    // phase 2: heads
    int wave = tid >> 6, lane = tid & 63;
    for (int j = wave; j < 19; j += 4) {
        const float4* w = (const float4*)(Wc + j * 2048);
        float p = 0.f;
        for (int k4 = lane; k4 < 512; k4 += 64) {
            float4 wv = w[k4];
            float4 rv = ((const float4*)yrow)[k4];
            p += rv.x * wv.x + rv.y * wv.y + rv.z * wv.z + rv.w * wv.w;
        }
#pragma unroll
        for (int off = 32; off; off >>= 1) p += __shfl_down(p, off);
        if (lane == 0) {
            if (j < 18) logits[b * NACT + j] = p + pol_b[j];
            else        value[b] = p + val_b[0];
        }
    }
}

// ---------------------------------------------------------------------------
extern "C" void kernel_launch(void* const* d_in, const int* in_sizes, int n_in,
                              void* d_out, int out_size, void* d_ws, size_t ws_size,
                              hipStream_t stream)
{
    const float* obs        = (const float*)d_in[0];
    const float* conv_state = (const float*)d_in[1];
    const float* ssm_state  = (const float*)d_in[2];
    const float* in_proj_w  = (const float*)d_in[3];
    const float* in_proj_b  = (const float*)d_in[4];
    const float* mamba_in_w = (const float*)d_in[5];
    const float* conv_w     = (const float*)d_in[6];
    const float* conv_b     = (const float*)d_in[7];
    const float* x_proj_w   = (const float*)d_in[8];
    const float* dt_w       = (const float*)d_in[9];
    const float* dt_b       = (const float*)d_in[10];
    const float* A_log      = (const float*)d_in[11];
    const float* Dvec       = (const float*)d_in[12];
    const float* out_proj_w = (const float*)d_in[13];
    const float* pol_w      = (const float*)d_in[14];
    const float* pol_b      = (const float*)d_in[15];
    const float* val_w      = (const float*)d_in[16];
    const float* val_b      = (const float*)d_in[17];

    // workspace layout (bytes)
    char* ws = (char*)d_ws;
    unsigned short* obs_bf    = (unsigned short*)(ws + 0);          // 2048x512 bf16
    unsigned short* w1_bf     = (unsigned short*)(ws + 2097152);    // 1024x512
    unsigned short* w2_bf     = (unsigned short*)(ws + 3145728);    // 4096x1024
    unsigned short* w3_bf     = (unsigned short*)(ws + 11534336);   // 128x2048 (padded)
    float*          A_neg     = (float*)(ws + 12058624);            // 2048x16
    unsigned short* h_bf      = (unsigned short*)(ws + 12189696);   // 2048x1024
    float*          x_conv    = (float*)(ws + 16384000);            // 2048x2048 fp32
    unsigned short* x_conv_bf = (unsigned short*)(ws + 33161216);   // 2048x2048 bf16
    float*          zs        = (float*)(ws + 41549824);            // 2048x2048 fp32
    float*          g3_part   = (float*)(ws + 58327040);            // 8x2048x128
    float*          x_db      = (float*)(ws + 66715648);            // 2048x96
    float*          Wc        = (float*)(ws + 67502080);            // 19x2048
    // total = 67,657,728 bytes
    if (ws_size < 67657728) return;  // insufficient workspace -> fail loudly

    float* logits   = (float*)d_out;                       // 2048x18
    float* value    = logits + (size_t)BATCH * NACT;       // 2048
    float* conv_out = value + BATCH;                       // 2048x2048x4
    float* ssm_out  = conv_out + (size_t)BATCH * DINNER * 4;  // 2048x2048x16

    // convert + fold_heads (Wc = [pol_w; val_w] @ out_proj_w)
    convert_fold_kernel<<<6072, 256, 0, stream>>>(
        obs, in_proj_w, mamba_in_w, x_proj_w, A_log, out_proj_w, pol_w, val_w,
        obs_bf, w1_bf, w2_bf, w3_bf, A_neg, Wc);

    // G1: h = obs @ in_proj_w.T + b  -> bf16
    gemm_bt<1, 1, 0><<<dim3(16, 8), 256, 0, stream>>>(
        (const short*)obs_bf, (const short*)w1_bf, h_bf, in_proj_b, 2048, 1024, 512, 0);

    // G2: xz = h @ mamba_in_w.T with fused conv (x half) + z*sig(z) (z half)
    gemm_g2<<<dim3(16, 32), 256, 0, stream>>>(
        (const short*)h_bf, (const short*)w2_bf, conv_state, conv_w, conv_b,
        conv_out, x_conv, x_conv_bf, zs, 1024);

    // G3: x_db = x_conv @ x_proj_w.T  (N padded 96->128, split-K=8)
    gemm_bt<0, 0, 1><<<dim3(16, 1, 8), 256, 0, stream>>>(
        (const short*)x_conv_bf, (const short*)w3_bf, g3_part, nullptr, 2048, 128, 2048, 256);

    // split-K reduce: x_db[2048][96] (single pass over g3_part)
    reduce_g3<<<768, 256, 0, stream>>>(g3_part, x_db);

    // fused dt + SSM + heads
    ssm_heads_kernel<<<2048, 256, 0, stream>>>(
        ssm_state, x_conv, zs, x_db, dt_w, dt_b, A_neg, Dvec, Wc, pol_b, val_b,
        ssm_out, logits, value);
}

// Round 6
// 826.946 us; speedup vs baseline: 1.1486x; 1.1228x over previous
//
#include <hip/hip_runtime.h>
#include <hip/hip_bf16.h>
#include <math.h>

// MambaActorCritic: B=2048, OBS=512, D_MODEL=1024, D_INNER=2048, D_STATE=16,
// D_CONV=4, DT_RANK=64, ACT=18. All inputs/outputs fp32; big GEMMs in bf16 MFMA.
//
// v7 changes vs v6 (929us) / v4 (859us):
//  - ssm_heads UN-FUSED into dt_kernel + ssm_kernel + heads_kernel. The fused
//    block-per-row kernel was convoy-limited (occupancy tracked dur: 52%->240us,
//    31%->325us; VALU 14%, HBM 17% -- nothing busy). New ssm_kernel: ZERO LDS,
//    ZERO barriers, 4-lane q-split (1KB/wave contiguous), grid-stride unroll-4
//    with wave-span stride so every load instruction is coalesced; B/C via
//    broadcast float4 loads. dt/heads are v2's proven separate kernels.
//  - NT stores reverted (measured neutral v5->v6).

#define BATCH 2048
#define OBSD 512
#define DMODEL 1024
#define DINNER 2048
#define DSTATE 16
#define DTRANK 64
#define NACT 18

typedef __attribute__((ext_vector_type(8))) short shortx8;
typedef __attribute__((ext_vector_type(4))) float floatx4;

__device__ inline float sig_(float x) { return 1.f / (1.f + __expf(-x)); }

__device__ inline unsigned short bfc(float x) {
    __hip_bfloat16 h = __float2bfloat16(x);
    return *(unsigned short*)&h;
}

__device__ inline void store_bf4(unsigned short* dst, float4 v) {
    ushort4 u;
    u.x = bfc(v.x); u.y = bfc(v.y); u.z = bfc(v.z); u.w = bfc(v.w);
    *(ushort4*)dst = u;
}

// ---------------------------------------------------------------------------
// convert (blocks 0..5919) + fold_heads (blocks 5920..6071).
// ---------------------------------------------------------------------------
__global__ __launch_bounds__(256) void convert_fold_kernel(
    const float* __restrict__ obs, const float* __restrict__ w1,
    const float* __restrict__ w2, const float* __restrict__ w3,
    const float* __restrict__ Alog, const float* __restrict__ opw,
    const float* __restrict__ pol_w, const float* __restrict__ val_w,
    unsigned short* __restrict__ obs_bf, unsigned short* __restrict__ w1_bf,
    unsigned short* __restrict__ w2_bf, unsigned short* __restrict__ w3_bf,
    float* __restrict__ A_neg, float* __restrict__ Wc)
{
    int blk = blockIdx.x;
    if (blk >= 5920) {
        __shared__ float hw[1024];
        int idx = blk - 5920;        // 0..151
        int j = idx % 19;
        int dblk = idx / 19;         // 0..7
        const float* src = (j < 18) ? (pol_w + j * 1024) : val_w;
        for (int t = threadIdx.x; t < 1024; t += 256) hw[t] = src[t];
        __syncthreads();
        int d = dblk * 256 + threadIdx.x;
        float acc = 0.f;
#pragma unroll 8
        for (int m = 0; m < 1024; ++m)
            acc += hw[m] * opw[(size_t)m * 2048 + d];
        Wc[j * 2048 + d] = acc;
        return;
    }
    int g = blk * 256 + threadIdx.x;
    if (g < 262144) {
        store_bf4(obs_bf + g * 4, ((const float4*)obs)[g]);
    } else if (g < 393216) {
        int t = g - 262144;
        store_bf4(w1_bf + t * 4, ((const float4*)w1)[t]);
    } else if (g < 1441792) {
        int t = g - 393216;
        store_bf4(w2_bf + t * 4, ((const float4*)w2)[t]);
    } else if (g < 1507328) {
        int t = g - 1441792;
        int e = t * 4;
        int n = e >> 11;
        int k = e & 2047;
        float4 v = {0.f, 0.f, 0.f, 0.f};
        if (n < 96) v = *(const float4*)(w3 + n * 2048 + k);
        store_bf4(w3_bf + e, v);
    } else {
        int t = g - 1507328;  // < 8192
        float4 v = ((const float4*)Alog)[t];
        float4 o = {-__expf(v.x), -__expf(v.y), -__expf(v.z), -__expf(v.w)};
        ((float4*)A_neg)[t] = o;
    }
}

// ---------------------------------------------------------------------------
// staging helper: one 128x32 bf16 tile pair via global_load_lds width-16.
// ---------------------------------------------------------------------------
__device__ __forceinline__ void stage_tile(
    const short* Abase, const short* Bbase, short* As, short* Bs,
    int K, int k0, int wave, int r0, int c0, int r1, int c1)
{
    __builtin_amdgcn_global_load_lds(
        (const __attribute__((address_space(1))) unsigned int*)(Abase + (size_t)r0 * K + k0 + c0),
        (__attribute__((address_space(3))) unsigned int*)(As + wave * 512), 16, 0, 0);
    __builtin_amdgcn_global_load_lds(
        (const __attribute__((address_space(1))) unsigned int*)(Abase + (size_t)r1 * K + k0 + c1),
        (__attribute__((address_space(3))) unsigned int*)(As + 2048 + wave * 512), 16, 0, 0);
    __builtin_amdgcn_global_load_lds(
        (const __attribute__((address_space(1))) unsigned int*)(Bbase + (size_t)r0 * K + k0 + c0),
        (__attribute__((address_space(3))) unsigned int*)(Bs + wave * 512), 16, 0, 0);
    __builtin_amdgcn_global_load_lds(
        (const __attribute__((address_space(1))) unsigned int*)(Bbase + (size_t)r1 * K + k0 + c1),
        (__attribute__((address_space(3))) unsigned int*)(Bs + 2048 + wave * 512), 16, 0, 0);
}

// ---------------------------------------------------------------------------
// bf16 MFMA GEMM: C[M,N] = A[M,K] * B[N,K]^T. 128x128 tile, 4 waves, BK=32,
// double-buffered 2-phase K-loop (stage t+1 || compute t).
// ---------------------------------------------------------------------------
template <int BF16OUT, int BIAS, int SPLITK>
__global__ __launch_bounds__(256) void gemm_bt(
    const short* __restrict__ A, const short* __restrict__ Bm,
    void* __restrict__ Cout, const float* __restrict__ bias,
    int M, int N, int K, int ksplit_len)
{
    __shared__ short As[2][128 * 32];
    __shared__ short Bs[2][128 * 32];

    const int tid  = threadIdx.x;
    const int wave = tid >> 6;
    const int lane = tid & 63;
    const int quad = lane >> 4;
    const int l16  = lane & 15;
    const int wm   = (wave & 1) << 6;
    const int wn   = (wave >> 1) << 6;
    const int bm   = blockIdx.x;
    const int bn   = blockIdx.y;

    int kbeg = 0, kend = K;
    if (SPLITK) { kbeg = blockIdx.z * ksplit_len; kend = kbeg + ksplit_len; }

    floatx4 acc[4][4] = {};

    const int v0 = tid * 8;
    const int r0 = v0 >> 5, c0 = v0 & 31;
    const int v1 = (256 + tid) * 8;
    const int r1 = v1 >> 5, c1 = v1 & 31;

    const short* Abase = A + (size_t)bm * 128 * K;
    const short* Bbase = Bm + (size_t)bn * 128 * K;

    stage_tile(Abase, Bbase, As[0], Bs[0], K, kbeg, wave, r0, c0, r1, c1);
    __syncthreads();  // vmcnt(0) drain -> buf0 ready

    int cur = 0;
    for (int k0 = kbeg; k0 < kend; k0 += 32) {
        if (k0 + 32 < kend)
            stage_tile(Abase, Bbase, As[cur ^ 1], Bs[cur ^ 1], K, k0 + 32,
                       wave, r0, c0, r1, c1);
        shortx8 af[4], bfv[4];
#pragma unroll
        for (int i = 0; i < 4; ++i)
            af[i] = *(const shortx8*)(As[cur] + (wm + i * 16 + l16) * 32 + quad * 8);
#pragma unroll
        for (int j = 0; j < 4; ++j)
            bfv[j] = *(const shortx8*)(Bs[cur] + (wn + j * 16 + l16) * 32 + quad * 8);
#pragma unroll
        for (int i = 0; i < 4; ++i)
#pragma unroll
            for (int j = 0; j < 4; ++j)
                acc[i][j] = __builtin_amdgcn_mfma_f32_16x16x32_bf16(af[i], bfv[j], acc[i][j], 0, 0, 0);
        __syncthreads();  // drains next-stage vmcnt; next iter reads buf^1
        cur ^= 1;
    }

    // epilogue: C/D layout col(n)=lane&15, row(m)=quad*4+reg  [m89-verified]
    if (BF16OUT) {
        unsigned short* C = (unsigned short*)Cout;
#pragma unroll
        for (int i = 0; i < 4; ++i) {
            int gm = bm * 128 + wm + i * 16 + quad * 4;
#pragma unroll
            for (int j = 0; j < 4; ++j) {
                int gn = bn * 128 + wn + j * 16 + l16;
                float bv = BIAS ? bias[gn] : 0.f;
#pragma unroll
                for (int r = 0; r < 4; ++r)
                    C[(size_t)(gm + r) * N + gn] = bfc(acc[i][j][r] + bv);
            }
        }
    } else {
        float* C = (float*)Cout;
        if (SPLITK) C += (size_t)blockIdx.z * M * N;
#pragma unroll
        for (int i = 0; i < 4; ++i) {
            int gm = bm * 128 + wm + i * 16 + quad * 4;
#pragma unroll
            for (int j = 0; j < 4; ++j) {
                int gn = bn * 128 + wn + j * 16 + l16;
                float bv = BIAS ? bias[gn] : 0.f;
#pragma unroll
                for (int r = 0; r < 4; ++r)
                    C[(size_t)(gm + r) * N + gn] = acc[i][j][r] + bv;
            }
        }
    }
}

// ---------------------------------------------------------------------------
// G2 with fused conv/z epilogue: xz = h @ mamba_in_w.T (M=2048, N=4096, K=1024)
// ---------------------------------------------------------------------------
__global__ __launch_bounds__(256) void gemm_g2(
    const short* __restrict__ A, const short* __restrict__ Bm,
    const float* __restrict__ conv_state, const float* __restrict__ conv_w,
    const float* __restrict__ conv_b, float* __restrict__ conv_out,
    float* __restrict__ x_conv, unsigned short* __restrict__ x_conv_bf,
    float* __restrict__ zs, int K)
{
    __shared__ short As[2][128 * 32];
    __shared__ short Bs[2][128 * 32];

    const int tid  = threadIdx.x;
    const int wave = tid >> 6;
    const int lane = tid & 63;
    const int quad = lane >> 4;
    const int l16  = lane & 15;
    const int wm   = (wave & 1) << 6;
    const int wn   = (wave >> 1) << 6;
    const int bm   = blockIdx.x;
    const int bn   = blockIdx.y;

    floatx4 acc[4][4] = {};

    const int v0 = tid * 8;
    const int r0 = v0 >> 5, c0 = v0 & 31;
    const int v1 = (256 + tid) * 8;
    const int r1 = v1 >> 5, c1 = v1 & 31;

    const short* Abase = A + (size_t)bm * 128 * K;
    const short* Bbase = Bm + (size_t)bn * 128 * K;

    stage_tile(Abase, Bbase, As[0], Bs[0], K, 0, wave, r0, c0, r1, c1);
    __syncthreads();

    int cur = 0;
    for (int k0 = 0; k0 < K; k0 += 32) {
        if (k0 + 32 < K)
            stage_tile(Abase, Bbase, As[cur ^ 1], Bs[cur ^ 1], K, k0 + 32,
                       wave, r0, c0, r1, c1);
        shortx8 af[4], bfv[4];
#pragma unroll
        for (int i = 0; i < 4; ++i)
            af[i] = *(const shortx8*)(As[cur] + (wm + i * 16 + l16) * 32 + quad * 8);
#pragma unroll
        for (int j = 0; j < 4; ++j)
            bfv[j] = *(const shortx8*)(Bs[cur] + (wn + j * 16 + l16) * 32 + quad * 8);
#pragma unroll
        for (int i = 0; i < 4; ++i)
#pragma unroll
            for (int j = 0; j < 4; ++j)
                acc[i][j] = __builtin_amdgcn_mfma_f32_16x16x32_bf16(af[i], bfv[j], acc[i][j], 0, 0, 0);
        __syncthreads();
        cur ^= 1;
    }

    // fused epilogue; bn<16 -> x half, else z half (block-uniform branch)
    if (bn < 16) {
#pragma unroll
        for (int j = 0; j < 4; ++j) {
            int d = bn * 128 + wn + j * 16 + l16;          // 0..2047
            float4 w4 = *(const float4*)(conv_w + d * 4);
            float cb = conv_b[d];
#pragma unroll
            for (int i = 0; i < 4; ++i) {
                int gm = bm * 128 + wm + i * 16 + quad * 4;
#pragma unroll
                for (int r = 0; r < 4; ++r) {
                    size_t idx = (size_t)(gm + r) * 2048 + d;
                    float xv = acc[i][j][r];
                    float4 cs = *(const float4*)(conv_state + idx * 4);
                    float s = cs.y * w4.x + cs.z * w4.y + cs.w * w4.z + xv * w4.w + cb;
                    float xc = s * sig_(s);
                    float4 outv = {cs.y, cs.z, cs.w, xv};
                    *(float4*)(conv_out + idx * 4) = outv;
                    x_conv[idx] = xc;
                    x_conv_bf[idx] = bfc(xc);
                }
            }
        }
    } else {
#pragma unroll
        for (int j = 0; j < 4; ++j) {
            int d = bn * 128 + wn + j * 16 + l16 - 2048;   // 0..2047
#pragma unroll
            for (int i = 0; i < 4; ++i) {
                int gm = bm * 128 + wm + i * 16 + quad * 4;
#pragma unroll
                for (int r = 0; r < 4; ++r) {
                    float zv = acc[i][j][r];
                    zs[(size_t)(gm + r) * 2048 + d] = zv * sig_(zv);
                }
            }
        }
    }
}

// sum split-K partials: x_db[b][n] (n<96) = sum_z part[z][b][n] (ld 128)
__global__ __launch_bounds__(256) void reduce_g3(
    const float* __restrict__ part, float* __restrict__ x_db)
{
    int idx = blockIdx.x * 256 + threadIdx.x;  // over 2048*96
    int b = idx / 96, n = idx - b * 96;
    float s = 0.f;
#pragma unroll
    for (int z = 0; z < 8; ++z)
        s += part[(size_t)z * BATCH * 128 + b * 128 + n];
    x_db[idx] = s;
}

// dt_full = softplus(x_db[:, :64] @ dt_w.T + dt_b); 8 batch rows per block.
__global__ __launch_bounds__(256) void dt_kernel(
    const float* __restrict__ x_db, const float* __restrict__ dt_w,
    const float* __restrict__ dt_b, float* __restrict__ dt_full)
{
    __shared__ float dtp[8][64];
    int tid = threadIdx.x;
    int b0 = blockIdx.y * 8;
    {
        int bb = tid >> 5, k = tid & 31;
        dtp[bb][k]      = x_db[(b0 + bb) * 96 + k];
        dtp[bb][k + 32] = x_db[(b0 + bb) * 96 + k + 32];
    }
    __syncthreads();
    int d = blockIdx.x * 256 + tid;
    float acc[8];
    float bv = dt_b[d];
#pragma unroll
    for (int bb = 0; bb < 8; ++bb) acc[bb] = bv;
    const float4* w = (const float4*)(dt_w + d * 64);
#pragma unroll
    for (int k4 = 0; k4 < 16; ++k4) {
        float4 wv = w[k4];
#pragma unroll
        for (int bb = 0; bb < 8; ++bb) {
            acc[bb] += dtp[bb][k4 * 4 + 0] * wv.x + dtp[bb][k4 * 4 + 1] * wv.y +
                       dtp[bb][k4 * 4 + 2] * wv.z + dtp[bb][k4 * 4 + 3] * wv.w;
        }
    }
#pragma unroll
    for (int bb = 0; bb < 8; ++bb) {
        float a = acc[bb];
        float sp = a > 20.f ? a : log1pf(__expf(a));
        dt_full[(size_t)(b0 + bb) * 2048 + d] = sp;
    }
}

// ---------------------------------------------------------------------------
// SSM state update: flat, NO LDS, NO barriers. 4 lanes per channel (q=tid&3),
// grid-stride unroll-4 where step u jumps by a QUARTER of B*D so every load
// instruction stays fully coalesced (wave = 16 consecutive channels = 1KB).
// B/C read as broadcast float4 from x_db. y written fp32 (16 lanes/wave, 64B).
// ---------------------------------------------------------------------------
__global__ __launch_bounds__(256) void ssm_kernel(
    const float* __restrict__ ssm_state, const float* __restrict__ x_conv,
    const float* __restrict__ dt_full, const float* __restrict__ zs,
    const float* __restrict__ x_db, const float* __restrict__ A_neg,
    const float* __restrict__ Dvec, float* __restrict__ ssm_out,
    float* __restrict__ y)
{
    const int q   = threadIdx.x & 3;
    const int gid = blockIdx.x * 64 + (threadIdx.x >> 2);  // 0..1048575
    const size_t QSTRIDE = (size_t)BATCH * DINNER / 4;     // 1048576
#pragma unroll
    for (int u = 0; u < 4; ++u) {
        size_t idx = (size_t)gid + (size_t)u * QSTRIDE;
        int b = (int)(idx >> 11);
        int d = (int)(idx & 2047);
        float xc  = x_conv[idx];
        float dtv = dt_full[idx];
        float zv  = zs[idx];
        float Dd  = Dvec[d];
        floatx4 Bv = *(const floatx4*)(x_db + b * 96 + 64 + q * 4);
        floatx4 Cv = *(const floatx4*)(x_db + b * 96 + 80 + q * 4);
        floatx4 s  = *(const floatx4*)(ssm_state + idx * 16 + q * 4);
        floatx4 a  = *(const floatx4*)(A_neg + (size_t)d * 16 + q * 4);
        float xdt = xc * dtv;
        floatx4 o;
        o.x = s.x * __expf(dtv * a.x) + xdt * Bv.x;
        o.y = s.y * __expf(dtv * a.y) + xdt * Bv.y;
        o.z = s.z * __expf(dtv * a.z) + xdt * Bv.z;
        o.w = s.w * __expf(dtv * a.w) + xdt * Bv.w;
        *(floatx4*)(ssm_out + idx * 16 + q * 4) = o;
        float p = o.x * Cv.x + o.y * Cv.y + o.z * Cv.z + o.w * Cv.w;
        p += __shfl_xor(p, 1);
        p += __shfl_xor(p, 2);
        if (q == 0) y[idx] = (p + Dd * xc) * zv;
    }
}

// logits = y @ Wc.T + pol_b (j<18); value = y @ Wc[18] + val_b
__global__ __launch_bounds__(256) void heads_kernel(
    const float* __restrict__ y, const float* __restrict__ Wc,
    const float* __restrict__ pol_b, const float* __restrict__ val_b,
    float* __restrict__ logits, float* __restrict__ value)
{
    __shared__ __align__(16) float row[2048];
    int b = blockIdx.x;
    int tid = threadIdx.x;
    const float4* src = (const float4*)(y + (size_t)b * 2048);
    ((float4*)row)[tid]       = src[tid];
    ((float4*)row)[tid + 256] = src[tid + 256];
    __syncthreads();
    int wave = tid >> 6, lane = tid & 63;
    for (int j = wave; j < 19; j += 4) {
        const float4* w = (const float4*)(Wc + j * 2048);
        float p = 0.f;
        for (int k4 = lane; k4 < 512; k4 += 64) {
            float4 wv = w[k4];
            float4 rv = ((const float4*)row)[k4];
            p += rv.x * wv.x + rv.y * wv.y + rv.z * wv.z + rv.w * wv.w;
        }
#pragma unroll
        for (int off = 32; off; off >>= 1) p += __shfl_down(p, off);
        if (lane == 0) {
            if (j < 18) logits[b * NACT + j] = p + pol_b[j];
            else        value[b] = p + val_b[0];
        }
    }
}

// ---------------------------------------------------------------------------
extern "C" void kernel_launch(void* const* d_in, const int* in_sizes, int n_in,
                              void* d_out, int out_size, void* d_ws, size_t ws_size,
                              hipStream_t stream)
{
    const float* obs        = (const float*)d_in[0];
    const float* conv_state = (const float*)d_in[1];
    const float* ssm_state  = (const float*)d_in[2];
    const float* in_proj_w  = (const float*)d_in[3];
    const float* in_proj_b  = (const float*)d_in[4];
    const float* mamba_in_w = (const float*)d_in[5];
    const float* conv_w     = (const float*)d_in[6];
    const float* conv_b     = (const float*)d_in[7];
    const float* x_proj_w   = (const float*)d_in[8];
    const float* dt_w       = (const float*)d_in[9];
    const float* dt_b       = (const float*)d_in[10];
    const float* A_log      = (const float*)d_in[11];
    const float* Dvec       = (const float*)d_in[12];
    const float* out_proj_w = (const float*)d_in[13];
    const float* pol_w      = (const float*)d_in[14];
    const float* pol_b      = (const float*)d_in[15];
    const float* val_w      = (const float*)d_in[16];
    const float* val_b      = (const float*)d_in[17];

    // workspace layout (bytes)
    char* ws = (char*)d_ws;
    unsigned short* obs_bf    = (unsigned short*)(ws + 0);          // 2048x512 bf16
    unsigned short* w1_bf     = (unsigned short*)(ws + 2097152);    // 1024x512
    unsigned short* w2_bf     = (unsigned short*)(ws + 3145728);    // 4096x1024
    unsigned short* w3_bf     = (unsigned short*)(ws + 11534336);   // 128x2048 (padded)
    float*          A_neg     = (float*)(ws + 12058624);            // 2048x16
    unsigned short* h_bf      = (unsigned short*)(ws + 12189696);   // 2048x1024
    float*          x_conv    = (float*)(ws + 16384000);            // 2048x2048 fp32
    unsigned short* x_conv_bf = (unsigned short*)(ws + 33161216);   // 2048x2048 bf16
    float*          zs        = (float*)(ws + 41549824);            // 2048x2048 fp32
    float*          g3_part   = (float*)(ws + 58327040);            // 8x2048x128
    float*          x_db      = (float*)(ws + 66715648);            // 2048x96
    float*          Wc        = (float*)(ws + 67502080);            // 19x2048
    float*          dt_full   = (float*)(ws + 67657728);            // 2048x2048
    float*          yv        = (float*)(ws + 84434944);            // 2048x2048
    // total = 101,212,160 bytes
    if (ws_size < 101212160) return;  // insufficient workspace -> fail loudly

    float* logits   = (float*)d_out;                       // 2048x18
    float* value    = logits + (size_t)BATCH * NACT;       // 2048
    float* conv_out = value + BATCH;                       // 2048x2048x4
    float* ssm_out  = conv_out + (size_t)BATCH * DINNER * 4;  // 2048x2048x16

    // convert + fold_heads (Wc = [pol_w; val_w] @ out_proj_w)
    convert_fold_kernel<<<6072, 256, 0, stream>>>(
        obs, in_proj_w, mamba_in_w, x_proj_w, A_log, out_proj_w, pol_w, val_w,
        obs_bf, w1_bf, w2_bf, w3_bf, A_neg, Wc);

    // G1: h = obs @ in_proj_w.T + b  -> bf16
    gemm_bt<1, 1, 0><<<dim3(16, 8), 256, 0, stream>>>(
        (const short*)obs_bf, (const short*)w1_bf, h_bf, in_proj_b, 2048, 1024, 512, 0);

    // G2: xz = h @ mamba_in_w.T with fused conv (x half) + z*sig(z) (z half)
    gemm_g2<<<dim3(16, 32), 256, 0, stream>>>(
        (const short*)h_bf, (const short*)w2_bf, conv_state, conv_w, conv_b,
        conv_out, x_conv, x_conv_bf, zs, 1024);

    // G3: x_db = x_conv @ x_proj_w.T  (N padded 96->128, split-K=8)
    gemm_bt<0, 0, 1><<<dim3(16, 1, 8), 256, 0, stream>>>(
        (const short*)x_conv_bf, (const short*)w3_bf, g3_part, nullptr, 2048, 128, 2048, 256);

    // split-K reduce: x_db[2048][96]
    reduce_g3<<<768, 256, 0, stream>>>(g3_part, x_db);

    // dt_full
    dt_kernel<<<dim3(8, 256), 256, 0, stream>>>(x_db, dt_w, dt_b, dt_full);

    // SSM state update (flat, barrier-free)
    ssm_kernel<<<16384, 256, 0, stream>>>(
        ssm_state, x_conv, dt_full, zs, x_db, A_neg, Dvec, ssm_out, yv);

    // heads
    heads_kernel<<<2048, 256, 0, stream>>>(yv, Wc, pol_b, val_b, logits, value);
}